// Round 8
// baseline (282.839 us; speedup 1.0000x reference)
//
#include <hip/hip_runtime.h>
#include <hip/hip_bf16.h>

using bf16 = __hip_bfloat16;
typedef unsigned int u32x4 __attribute__((ext_vector_type(4)));
typedef float f32x4 __attribute__((ext_vector_type(4)));
typedef __bf16 bf16x8 __attribute__((ext_vector_type(8)));

#define DEVI __device__ __forceinline__

DEVI f32x4 mfma16(u32x4 a, u32x4 b, f32x4 c) {
    return __builtin_amdgcn_mfma_f32_16x16x32_bf16(
        __builtin_bit_cast(bf16x8, a), __builtin_bit_cast(bf16x8, b), c, 0, 0, 0);
}

struct bf8 { bf16 h[8]; };

DEVI u32x4 pack8(f32x4 lo, f32x4 hi) {
    bf8 t;
#pragma unroll
    for (int i = 0; i < 4; i++) {
        t.h[i] = __float2bfloat16(lo[i]);
        t.h[4 + i] = __float2bfloat16(hi[i]);
    }
    return __builtin_bit_cast(u32x4, t);
}

// RNE-packed 4x bf16 -> 64-bit
DEVI unsigned long long pk4(float a, float b, float c, float d) {
    union { unsigned long long u; bf16 h[4]; } t;
    t.h[0] = __float2bfloat16(a); t.h[1] = __float2bfloat16(b);
    t.h[2] = __float2bfloat16(c); t.h[3] = __float2bfloat16(d);
    return t.u;
}

// truncating bf16x2 pack (1 op)
DEVI unsigned trunc2(float a, float b) {
    return __builtin_amdgcn_perm(__builtin_bit_cast(unsigned, b),
                                 __builtin_bit_cast(unsigned, a), 0x07060302);
}

// ------------- prep: WT[n][k] = (bf16)W[k][n] (5 mats) + xb = (bf16)x --------
__global__ __launch_bounds__(256) void prep(
    const float* __restrict__ Wq, const float* __restrict__ Wk,
    const float* __restrict__ Wv, const float* __restrict__ W1,
    const float* __restrict__ W2, const float* __restrict__ x,
    bf16* __restrict__ WT, bf16* __restrict__ xb)
{
    int b = blockIdx.x;
    if (b < 5120) {
        int w = b >> 10;
        const float* src = (w == 0) ? Wq : (w == 1) ? Wk : (w == 2) ? Wv : (w == 3) ? W1 : W2;
        int idx = (b & 1023) * 256 + threadIdx.x;   // idx = n*512 + k
        int n = idx >> 9, kk = idx & 511;
        WT[(size_t)w * 262144 + idx] = __float2bfloat16(src[kk * 512 + n]);
    } else {
        size_t i = ((size_t)(b - 5120) * 256 + threadIdx.x) * 8;
        f32x4 lo = *(const f32x4*)&x[i];
        f32x4 hi = *(const f32x4*)&x[i + 4];
        *(u32x4*)&xb[i] = pack8(lo, hi);
    }
}

// ------------- fused QKV GEMM: reg-prefetch pipeline + packed epilogues ------
__global__ __launch_bounds__(256) void gemm_qkv(
    const bf16* __restrict__ A, const bf16* __restrict__ WT,
    const float* __restrict__ bqp, const float* __restrict__ bkp, const float* __restrict__ bvp,
    bf16* __restrict__ qb, bf16* __restrict__ kb, bf16* __restrict__ vT)
{
    __shared__ __align__(16) bf16 As[128 * 32];
    __shared__ __align__(16) bf16 Bs[128 * 32];
    const int tid = threadIdx.x;
    const int lane = tid & 63, wave = tid >> 6;
    const int wm = (wave >> 1) * 64, wn = (wave & 1) * 64;
    const int wsel = blockIdx.y >> 2;                  // 0=q 1=k 2=v
    const int bm = blockIdx.x * 128, bn = (blockIdx.y & 3) * 128;
    const bf16* Bt = WT + (size_t)wsel * 262144;
    const float* bias = (wsel == 0) ? bqp : (wsel == 1) ? bkp : bvp;
    const int lm = lane & 15, lq = lane >> 4;

    const int r0 = tid >> 2, kc0 = (tid & 3) * 8;
    const bf16* Ap = A + (size_t)(bm + r0) * 512 + kc0;
    const bf16* Bp = Bt + (size_t)(bn + r0) * 512 + kc0;

    f32x4 acc[4][4];
#pragma unroll
    for (int i = 0; i < 4; i++)
#pragma unroll
        for (int j = 0; j < 4; j++) acc[i][j] = (f32x4){0.f, 0.f, 0.f, 0.f};

    u32x4 ar0 = *(const u32x4*)Ap;
    u32x4 ar1 = *(const u32x4*)(Ap + 64 * 512);
    u32x4 br0 = *(const u32x4*)Bp;
    u32x4 br1 = *(const u32x4*)(Bp + 64 * 512);

    for (int k0 = 0; k0 < 512; k0 += 32) {
        __syncthreads();   // prior frag reads done; drains prefetch (post-compute)
        *(u32x4*)&As[r0 * 32 + kc0] = ar0;
        *(u32x4*)&As[(r0 + 64) * 32 + kc0] = ar1;
        *(u32x4*)&Bs[r0 * 32 + kc0] = br0;
        *(u32x4*)&Bs[(r0 + 64) * 32 + kc0] = br1;
        __syncthreads();   // LDS valid
        if (k0 < 480) {    // issue next-tile loads: in flight across whole compute
            ar0 = *(const u32x4*)(Ap + k0 + 32);
            ar1 = *(const u32x4*)(Ap + 64 * 512 + k0 + 32);
            br0 = *(const u32x4*)(Bp + k0 + 32);
            br1 = *(const u32x4*)(Bp + 64 * 512 + k0 + 32);
        }
        u32x4 af[4], bfr[4];
#pragma unroll
        for (int i = 0; i < 4; i++) af[i] = *(const u32x4*)&As[(wm + i * 16 + lm) * 32 + lq * 8];
#pragma unroll
        for (int j = 0; j < 4; j++) bfr[j] = *(const u32x4*)&Bs[(wn + j * 16 + lm) * 32 + lq * 8];
        if (wsel < 2) {    // swapped: lane holds [row=..+lm][4 consecutive cols]
#pragma unroll
            for (int i = 0; i < 4; i++)
#pragma unroll
                for (int j = 0; j < 4; j++) acc[i][j] = mfma16(bfr[j], af[i], acc[i][j]);
        } else {           // normal: lane holds [4 consecutive rows][col=..+lm]
#pragma unroll
            for (int i = 0; i < 4; i++)
#pragma unroll
                for (int j = 0; j < 4; j++) acc[i][j] = mfma16(af[i], bfr[j], acc[i][j]);
        }
    }

    if (wsel < 2) {
        const float scale = (wsel == 0) ? 0.18033688f : 1.0f;   // log2e/8 into q
        bf16* dst = (wsel == 0) ? qb : kb;
#pragma unroll
        for (int i = 0; i < 4; i++) {
#pragma unroll
            for (int j = 0; j < 4; j++) {
                int row = bm + wm + i * 16 + lm;
                int colb = bn + wn + j * 16 + lq * 4;
                f32x4 b4 = *(const f32x4*)&bias[colb];
                *(unsigned long long*)&dst[(size_t)row * 512 + colb] =
                    pk4((acc[i][j][0] + b4[0]) * scale, (acc[i][j][1] + b4[1]) * scale,
                        (acc[i][j][2] + b4[2]) * scale, (acc[i][j][3] + b4[3]) * scale);
            }
        }
    } else {
#pragma unroll
        for (int i = 0; i < 4; i++) {
#pragma unroll
            for (int j = 0; j < 4; j++) {
                int col = bn + wn + j * 16 + lm;
                float bv = bias[col];
                int rowb = bm + wm + i * 16 + lq * 4;   // 4 consecutive nodes
                int btq = rowb >> 10, node = rowb & 1023;
                *(unsigned long long*)&vT[((size_t)((btq * 8 + (col >> 6)) * 64 + (col & 63))) * 1024 + node] =
                    pk4(acc[i][j][0] + bv, acc[i][j][1] + bv,
                        acc[i][j][2] + bv, acc[i][j][3] + bv);
            }
        }
    }
}

// ------------- FFN GEMM (RELU or plain), swapped orientation -----------------
template <bool RELU>
__global__ __launch_bounds__(256) void gemm_bt(
    const bf16* __restrict__ A, const bf16* __restrict__ Bt,
    const float* __restrict__ bias, bf16* __restrict__ C)
{
    __shared__ __align__(16) bf16 As[128 * 32];
    __shared__ __align__(16) bf16 Bs[128 * 32];
    const int tid = threadIdx.x;
    const int lane = tid & 63, wave = tid >> 6;
    const int wm = (wave >> 1) * 64, wn = (wave & 1) * 64;
    const int bm = blockIdx.x * 128, bn = blockIdx.y * 128;
    const int lm = lane & 15, lq = lane >> 4;

    const int r0 = tid >> 2, kc0 = (tid & 3) * 8;
    const bf16* Ap = A + (size_t)(bm + r0) * 512 + kc0;
    const bf16* Bp = Bt + (size_t)(bn + r0) * 512 + kc0;

    f32x4 acc[4][4];
#pragma unroll
    for (int i = 0; i < 4; i++)
#pragma unroll
        for (int j = 0; j < 4; j++) acc[i][j] = (f32x4){0.f, 0.f, 0.f, 0.f};

    u32x4 ar0 = *(const u32x4*)Ap;
    u32x4 ar1 = *(const u32x4*)(Ap + 64 * 512);
    u32x4 br0 = *(const u32x4*)Bp;
    u32x4 br1 = *(const u32x4*)(Bp + 64 * 512);

    for (int k0 = 0; k0 < 512; k0 += 32) {
        __syncthreads();
        *(u32x4*)&As[r0 * 32 + kc0] = ar0;
        *(u32x4*)&As[(r0 + 64) * 32 + kc0] = ar1;
        *(u32x4*)&Bs[r0 * 32 + kc0] = br0;
        *(u32x4*)&Bs[(r0 + 64) * 32 + kc0] = br1;
        __syncthreads();
        if (k0 < 480) {
            ar0 = *(const u32x4*)(Ap + k0 + 32);
            ar1 = *(const u32x4*)(Ap + 64 * 512 + k0 + 32);
            br0 = *(const u32x4*)(Bp + k0 + 32);
            br1 = *(const u32x4*)(Bp + 64 * 512 + k0 + 32);
        }
        u32x4 af[4], bfr[4];
#pragma unroll
        for (int i = 0; i < 4; i++) af[i] = *(const u32x4*)&As[(wm + i * 16 + lm) * 32 + lq * 8];
#pragma unroll
        for (int j = 0; j < 4; j++) bfr[j] = *(const u32x4*)&Bs[(wn + j * 16 + lm) * 32 + lq * 8];
#pragma unroll
        for (int i = 0; i < 4; i++)
#pragma unroll
            for (int j = 0; j < 4; j++) acc[i][j] = mfma16(bfr[j], af[i], acc[i][j]);
    }

#pragma unroll
    for (int i = 0; i < 4; i++) {
#pragma unroll
        for (int j = 0; j < 4; j++) {
            int row = bm + wm + i * 16 + lm;
            int colb = bn + wn + j * 16 + lq * 4;
            f32x4 b4 = *(const f32x4*)&bias[colb];
            float c0 = acc[i][j][0] + b4[0], c1 = acc[i][j][1] + b4[1];
            float c2 = acc[i][j][2] + b4[2], c3 = acc[i][j][3] + b4[3];
            if (RELU) {
                c0 = fmaxf(c0, 0.f); c1 = fmaxf(c1, 0.f);
                c2 = fmaxf(c2, 0.f); c3 = fmaxf(c3, 0.f);
            }
            *(unsigned long long*)&C[(size_t)row * 512 + colb] = pk4(c0, c1, c2, c3);
        }
    }
}

// ------------- flash attention: 2-wave blocks, pipelined staging -------------
// q (pre-scaled by log2e/8), k: [16384 x 512] bf16 ; vT: [(g)*64+d][1024] bf16
// o: [16384 x 512] f32.  grid(128 groups, 8 qtiles of 128 rows), 128 threads.
__global__ __launch_bounds__(128, 2) void attn_kernel(
    const bf16* __restrict__ q, const bf16* __restrict__ k,
    const bf16* __restrict__ vT, float* __restrict__ o)
{
    constexpr int KP = 72;   // 144 B stride: 16-B aligned, free 2-way
    constexpr int VP = 72;
    __shared__ __align__(16) bf16 Ks[64 * KP];        // [key][d]
    __shared__ __align__(16) bf16 Vs[64 * VP];        // [d][key]
    __shared__ __align__(16) bf16 Ps[2][64 * VP];     // per-wave [q(64)][key]

    const int tid = threadIdx.x, lane = tid & 63, wave = tid >> 6;
    const int group = blockIdx.x;          // bt*8 + h
    const int bt = group >> 3, hh = group & 7;
    const int lm = lane & 15, lq = lane >> 4;
    const int qrow0 = bt * 1024 + blockIdx.y * 128 + wave * 64;

    u32x4 qf[4][2];
#pragma unroll
    for (int tm = 0; tm < 4; tm++)
#pragma unroll
        for (int kk2 = 0; kk2 < 2; kk2++)
            qf[tm][kk2] = *(const u32x4*)&q[(size_t)(qrow0 + tm * 16 + lm) * 512 + hh * 64 + kk2 * 32 + lq * 8];

    const bf16* kbase = k + (size_t)(bt * 1024) * 512 + hh * 64;   // + row*512 + e
    const bf16* vbase = vT + (size_t)group * 64 * 1024;            // + d*1024 + key
    bf16* Pw = Ps[wave];

    // staging coords: 4 chunks of 16 rows, 128 threads cover 64 rows x 64 el
    const int rb = tid >> 3, e0 = (tid & 7) * 8;

    f32x4 accO[4][4];
#pragma unroll
    for (int tm = 0; tm < 4; tm++)
#pragma unroll
        for (int tn = 0; tn < 4; tn++) accO[tm][tn] = (f32x4){0.f, 0.f, 0.f, 0.f};
    float part[4] = {0.f, 0.f, 0.f, 0.f};

    u32x4 kreg[4], vreg[4];
#pragma unroll
    for (int s = 0; s < 4; s++) {
        kreg[s] = *(const u32x4*)&kbase[(size_t)(s * 16 + rb) * 512 + e0];
        vreg[s] = *(const u32x4*)&vbase[(size_t)(s * 16 + rb) * 1024 + e0];
    }

    for (int kt = 0; kt < 16; kt++) {
        __syncthreads();   // prior compute done; drains prefetch (post-compute)
#pragma unroll
        for (int s = 0; s < 4; s++) {
            *(u32x4*)&Ks[(s * 16 + rb) * KP + e0] = kreg[s];
            *(u32x4*)&Vs[(s * 16 + rb) * VP + e0] = vreg[s];
        }
        __syncthreads();   // staged tile visible
        if (kt < 15) {     // issue next-tile loads AFTER barrier: overlap compute
            const bf16* kn = kbase + (size_t)((kt + 1) * 64) * 512;
            const bf16* vn = vbase + (kt + 1) * 64;
#pragma unroll
            for (int s = 0; s < 4; s++) {
                kreg[s] = *(const u32x4*)&kn[(size_t)(s * 16 + rb) * 512 + e0];
                vreg[s] = *(const u32x4*)&vn[(size_t)(s * 16 + rb) * 1024 + e0];
            }
        }

        // S^T tiles: A=K (m=key), B=Q (n=q); C-frag rows = 4 consecutive keys
#pragma unroll
        for (int tk = 0; tk < 4; tk++) {
            u32x4 kf0 = *(const u32x4*)&Ks[(tk * 16 + lm) * KP + lq * 8];
            u32x4 kf1 = *(const u32x4*)&Ks[(tk * 16 + lm) * KP + 32 + lq * 8];
#pragma unroll
            for (int tm = 0; tm < 4; tm++) {
                f32x4 st = (f32x4){0.f, 0.f, 0.f, 0.f};
                st = mfma16(kf0, qf[tm][0], st);
                st = mfma16(kf1, qf[tm][1], st);
                float p0 = __builtin_amdgcn_exp2f(st[0]);
                float p1 = __builtin_amdgcn_exp2f(st[1]);
                float p2 = __builtin_amdgcn_exp2f(st[2]);
                float p3 = __builtin_amdgcn_exp2f(st[3]);
                part[tm] += (p0 + p1) + (p2 + p3);
                unsigned lo = trunc2(p0, p1), hi = trunc2(p2, p3);
                unsigned long long pk2 = ((unsigned long long)hi << 32) | lo;
                *(unsigned long long*)&Pw[(tm * 16 + lm) * VP + tk * 16 + lq * 4] = pk2;
            }
        }

        // O += P V   (A=P from LDS, B=V^T from LDS)
#pragma unroll
        for (int kc = 0; kc < 2; kc++) {
            u32x4 pf[4], vf[4];
#pragma unroll
            for (int tm = 0; tm < 4; tm++)
                pf[tm] = *(const u32x4*)&Pw[(tm * 16 + lm) * VP + kc * 32 + lq * 8];
#pragma unroll
            for (int tn = 0; tn < 4; tn++)
                vf[tn] = *(const u32x4*)&Vs[(tn * 16 + lm) * VP + kc * 32 + lq * 8];
#pragma unroll
            for (int tm = 0; tm < 4; tm++)
#pragma unroll
                for (int tn = 0; tn < 4; tn++)
                    accO[tm][tn] = mfma16(pf[tm], vf[tn], accO[tm][tn]);
        }
    }

    // final l reduction (across quads) and normalized store
#pragma unroll
    for (int tm = 0; tm < 4; tm++) {
        part[tm] += __shfl_xor(part[tm], 16);
        part[tm] += __shfl_xor(part[tm], 32);
    }
#pragma unroll
    for (int tm = 0; tm < 4; tm++)
#pragma unroll
        for (int r = 0; r < 4; r++) {
            float l = __shfl(part[tm], lq * 4 + r);   // lane lq*4+r holds l for q-row lq*4+r
            float linv = 1.0f / l;
#pragma unroll
            for (int tn = 0; tn < 4; tn++) {
                int row = qrow0 + tm * 16 + lq * 4 + r;
                int col = hh * 64 + tn * 16 + lm;
                o[(size_t)row * 512 + col] = accO[tm][tn][r] * linv;
            }
        }
}

// ------------- LayerNorm (one wave per 512-el row) ---------------------------
template <bool AF32, bool RES, bool OF32>
__global__ __launch_bounds__(256) void ln_kernel(
    const void* __restrict__ a, const float* __restrict__ res,
    const float* __restrict__ g, const float* __restrict__ bb, void* __restrict__ out)
{
    int row = blockIdx.x * 4 + (threadIdx.x >> 6);
    int lane = threadIdx.x & 63;
    size_t base = (size_t)row * 512 + lane * 8;
    int cbase = lane * 8;

    float x8[8];
    if (AF32) {
        const float* af = (const float*)a;
        f32x4 lo = *(const f32x4*)&af[base];
        f32x4 hi = *(const f32x4*)&af[base + 4];
#pragma unroll
        for (int i = 0; i < 4; i++) { x8[i] = lo[i]; x8[4 + i] = hi[i]; }
    } else {
        bf8 av = __builtin_bit_cast(bf8, *(const u32x4*)&((const bf16*)a)[base]);
#pragma unroll
        for (int i = 0; i < 8; i++) x8[i] = __bfloat162float(av.h[i]);
    }
    if (RES) {
        f32x4 lo = *(const f32x4*)&res[base];
        f32x4 hi = *(const f32x4*)&res[base + 4];
#pragma unroll
        for (int i = 0; i < 4; i++) { x8[i] += lo[i]; x8[4 + i] += hi[i]; }
    }

    float s = 0.f, s2 = 0.f;
#pragma unroll
    for (int i = 0; i < 8; i++) { s += x8[i]; s2 += x8[i] * x8[i]; }
#pragma unroll
    for (int off = 1; off < 64; off <<= 1) {
        s += __shfl_xor(s, off);
        s2 += __shfl_xor(s2, off);
    }
    float mean = s * (1.f / 512.f);
    float var = s2 * (1.f / 512.f) - mean * mean;
    float rstd = rsqrtf(var + 1e-5f);

    f32x4 g0 = *(const f32x4*)&g[cbase], g1 = *(const f32x4*)&g[cbase + 4];
    f32x4 b0 = *(const f32x4*)&bb[cbase], b1v = *(const f32x4*)&bb[cbase + 4];
    float y[8];
#pragma unroll
    for (int i = 0; i < 4; i++) {
        y[i] = (x8[i] - mean) * rstd * g0[i] + b0[i];
        y[4 + i] = (x8[4 + i] - mean) * rstd * g1[i] + b1v[i];
    }
    if (OF32) {
        float* op = (float*)out;
        *(f32x4*)&op[base] = (f32x4){y[0], y[1], y[2], y[3]};
        *(f32x4*)&op[base + 4] = (f32x4){y[4], y[5], y[6], y[7]};
    } else {
        bf8 ov;
#pragma unroll
        for (int i = 0; i < 8; i++) ov.h[i] = __float2bfloat16(y[i]);
        *(u32x4*)&((bf16*)out)[base] = __builtin_bit_cast(u32x4, ov);
    }
}

// ------------- launch --------------------------------------------------------
extern "C" void kernel_launch(void* const* d_in, const int* in_sizes, int n_in,
                              void* d_out, int out_size, void* d_ws, size_t ws_size,
                              hipStream_t stream)
{
    const float* x    = (const float*)d_in[0];
    const float* Wq   = (const float*)d_in[1];
    const float* bq   = (const float*)d_in[2];
    const float* Wk   = (const float*)d_in[3];
    const float* bk   = (const float*)d_in[4];
    const float* Wv   = (const float*)d_in[5];
    const float* bv   = (const float*)d_in[6];
    const float* ln_g = (const float*)d_in[7];
    const float* ln_b = (const float*)d_in[8];
    const float* W1   = (const float*)d_in[9];
    const float* b1   = (const float*)d_in[10];
    const float* W2   = (const float*)d_in[11];
    const float* b2   = (const float*)d_in[12];
    const float* lnffg = (const float*)d_in[13];
    const float* lnffb = (const float*)d_in[14];
    float* out = (float*)d_out;

    bf16* ws = (bf16*)d_ws;
    bf16* WT = ws;                        // 5 * 262144 bf16
    bf16* qb = ws + 5 * 262144;           // 8388608 bf16 each below
    bf16* kb = qb + 8388608;
    bf16* vT = kb + 8388608;
    bf16* vl = qb;                        // reuse (q dead after attention)
    bf16* f1 = kb;                        // reuse (k dead after attention)
    bf16* f2 = vT;                        // reuse (v dead after attention)
    bf16* xb = (bf16*)d_out;              // 16.7MB scratch; dead before attention writes O

    prep<<<9216, 256, 0, stream>>>(Wq, Wk, Wv, W1, W2, x, WT, xb);

    gemm_qkv<<<dim3(128, 12), 256, 0, stream>>>(xb, WT, bq, bk, bv, qb, kb, vT);

    attn_kernel<<<dim3(128, 8), 128, 0, stream>>>(qb, kb, vT, out);

    ln_kernel<true, true, false><<<4096, 256, 0, stream>>>(out, x, ln_g, ln_b, vl);

    dim3 gg(128, 4);
    gemm_bt<true> <<<gg, 256, 0, stream>>>(vl, WT + 3 * 262144, b1, f1);
    gemm_bt<false><<<gg, 256, 0, stream>>>(f1, WT + 4 * 262144, b2, f2);

    ln_kernel<false, false, true><<<4096, 256, 0, stream>>>(f2, nullptr, lnffg, lnffb, out);
}

// Round 9
// 259.962 us; speedup vs baseline: 1.0880x; 1.0880x over previous
//
#include <hip/hip_runtime.h>
#include <hip/hip_bf16.h>

using bf16 = __hip_bfloat16;
typedef unsigned int u32x4 __attribute__((ext_vector_type(4)));
typedef float f32x4 __attribute__((ext_vector_type(4)));
typedef __bf16 bf16x8 __attribute__((ext_vector_type(8)));

#define DEVI __device__ __forceinline__

DEVI f32x4 mfma16(u32x4 a, u32x4 b, f32x4 c) {
    return __builtin_amdgcn_mfma_f32_16x16x32_bf16(
        __builtin_bit_cast(bf16x8, a), __builtin_bit_cast(bf16x8, b), c, 0, 0, 0);
}

struct bf8 { bf16 h[8]; };

DEVI u32x4 pack8(f32x4 lo, f32x4 hi) {
    bf8 t;
#pragma unroll
    for (int i = 0; i < 4; i++) {
        t.h[i] = __float2bfloat16(lo[i]);
        t.h[4 + i] = __float2bfloat16(hi[i]);
    }
    return __builtin_bit_cast(u32x4, t);
}

// RNE-packed 4x bf16 -> 64-bit
DEVI unsigned long long pk4(float a, float b, float c, float d) {
    union { unsigned long long u; bf16 h[4]; } t;
    t.h[0] = __float2bfloat16(a); t.h[1] = __float2bfloat16(b);
    t.h[2] = __float2bfloat16(c); t.h[3] = __float2bfloat16(d);
    return t.u;
}

// truncating bf16x2 pack (1 op)
DEVI unsigned trunc2(float a, float b) {
    return __builtin_amdgcn_perm(__builtin_bit_cast(unsigned, b),
                                 __builtin_bit_cast(unsigned, a), 0x07060302);
}

// ------------- prep: WT[n][k] = (bf16)W[k][n] (5 mats) + xb = (bf16)x --------
__global__ __launch_bounds__(256) void prep(
    const float* __restrict__ Wq, const float* __restrict__ Wk,
    const float* __restrict__ Wv, const float* __restrict__ W1,
    const float* __restrict__ W2, const float* __restrict__ x,
    bf16* __restrict__ WT, bf16* __restrict__ xb)
{
    int b = blockIdx.x;
    if (b < 5120) {
        int w = b >> 10;
        const float* src = (w == 0) ? Wq : (w == 1) ? Wk : (w == 2) ? Wv : (w == 3) ? W1 : W2;
        int idx = (b & 1023) * 256 + threadIdx.x;   // idx = n*512 + k
        int n = idx >> 9, kk = idx & 511;
        WT[(size_t)w * 262144 + idx] = __float2bfloat16(src[kk * 512 + n]);
    } else {
        size_t i = ((size_t)(b - 5120) * 256 + threadIdx.x) * 8;
        f32x4 lo = *(const f32x4*)&x[i];
        f32x4 hi = *(const f32x4*)&x[i + 4];
        *(u32x4*)&xb[i] = pack8(lo, hi);
    }
}

// ------------- GEMM core: 128x128 tile, BK=64 (8 iters), reg-prefetch --------
// SP = 72: LDS row stride 144 B (16-B aligned, 36 words -> free 2-way).
#define GEMM_BODY(EPILOGUE)                                                          \
    constexpr int SP = 72;                                                           \
    __shared__ __align__(16) bf16 As[128 * SP];                                      \
    __shared__ __align__(16) bf16 Bs[128 * SP];                                      \
    const int tid = threadIdx.x;                                                     \
    const int lane = tid & 63, wave = tid >> 6;                                      \
    const int wm = (wave >> 1) * 64, wn = (wave & 1) * 64;                           \
    const int lm = lane & 15, lq = lane >> 4;                                        \
    const int sr = tid >> 3, sc = (tid & 7) * 8;   /* stage row base/col */          \
    const bf16* Ap = A + (size_t)(bm + sr) * 512 + sc;                               \
    const bf16* Bp = Bt + (size_t)(bn + sr) * 512 + sc;                              \
    f32x4 acc[4][4];                                                                 \
    _Pragma("unroll") for (int i = 0; i < 4; i++)                                    \
        _Pragma("unroll") for (int j = 0; j < 4; j++)                                \
            acc[i][j] = (f32x4){0.f, 0.f, 0.f, 0.f};                                 \
    u32x4 ar[4], br[4];                                                              \
    _Pragma("unroll") for (int p = 0; p < 4; p++) {                                  \
        ar[p] = *(const u32x4*)(Ap + (size_t)p * 32 * 512);                          \
        br[p] = *(const u32x4*)(Bp + (size_t)p * 32 * 512);                          \
    }                                                                                \
    for (int k0 = 0; k0 < 512; k0 += 64) {                                           \
        __syncthreads();                                                             \
        _Pragma("unroll") for (int p = 0; p < 4; p++) {                              \
            *(u32x4*)&As[(p * 32 + sr) * SP + sc] = ar[p];                           \
            *(u32x4*)&Bs[(p * 32 + sr) * SP + sc] = br[p];                           \
        }                                                                            \
        __syncthreads();                                                             \
        if (k0 < 448) {   /* post-barrier: in flight across whole compute phase */   \
            _Pragma("unroll") for (int p = 0; p < 4; p++) {                          \
                ar[p] = *(const u32x4*)(Ap + (size_t)p * 32 * 512 + k0 + 64);        \
                br[p] = *(const u32x4*)(Bp + (size_t)p * 32 * 512 + k0 + 64);        \
            }                                                                        \
        }                                                                            \
        _Pragma("unroll") for (int h = 0; h < 2; h++) {                              \
            u32x4 af[4], bfr[4];                                                     \
            _Pragma("unroll") for (int i = 0; i < 4; i++)                            \
                af[i] = *(const u32x4*)&As[(wm + i * 16 + lm) * SP + h * 32 + lq * 8]; \
            _Pragma("unroll") for (int j = 0; j < 4; j++)                            \
                bfr[j] = *(const u32x4*)&Bs[(wn + j * 16 + lm) * SP + h * 32 + lq * 8]; \
            EPILOGUE##_MMA                                                           \
        }                                                                            \
    }

#define SWAPPED_MMA                                                                  \
    _Pragma("unroll") for (int i = 0; i < 4; i++)                                    \
        _Pragma("unroll") for (int j = 0; j < 4; j++)                                \
            acc[i][j] = mfma16(bfr[j], af[i], acc[i][j]);
#define NORMAL_MMA                                                                   \
    _Pragma("unroll") for (int i = 0; i < 4; i++)                                    \
        _Pragma("unroll") for (int j = 0; j < 4; j++)                                \
            acc[i][j] = mfma16(af[i], bfr[j], acc[i][j]);

// ------------- fused QKV GEMM ------------------------------------------------
__global__ __launch_bounds__(256) void gemm_qkv(
    const bf16* __restrict__ A, const bf16* __restrict__ WT,
    const float* __restrict__ bqp, const float* __restrict__ bkp, const float* __restrict__ bvp,
    bf16* __restrict__ qb, bf16* __restrict__ kb, bf16* __restrict__ vT)
{
    const int wsel = blockIdx.y >> 2;                  // 0=q 1=k 2=v
    const int bm = blockIdx.x * 128, bn = (blockIdx.y & 3) * 128;
    const bf16* Bt = WT + (size_t)wsel * 262144;
    const float* bias = (wsel == 0) ? bqp : (wsel == 1) ? bkp : bvp;

    if (wsel < 2) {   // swapped orientation: lane holds [row][4 consecutive cols]
        GEMM_BODY(SWAPPED)
        const float scale = (wsel == 0) ? 0.18033688f : 1.0f;   // log2e/8 into q
        bf16* dst = (wsel == 0) ? qb : kb;
#pragma unroll
        for (int i = 0; i < 4; i++) {
#pragma unroll
            for (int j = 0; j < 4; j++) {
                int row = bm + wm + i * 16 + lm;
                int colb = bn + wn + j * 16 + lq * 4;
                f32x4 b4 = *(const f32x4*)&bias[colb];
                *(unsigned long long*)&dst[(size_t)row * 512 + colb] =
                    pk4((acc[i][j][0] + b4[0]) * scale, (acc[i][j][1] + b4[1]) * scale,
                        (acc[i][j][2] + b4[2]) * scale, (acc[i][j][3] + b4[3]) * scale);
            }
        }
    } else {          // normal orientation: lane holds [4 consecutive rows][col] -> vT pack
        GEMM_BODY(NORMAL)
#pragma unroll
        for (int i = 0; i < 4; i++) {
#pragma unroll
            for (int j = 0; j < 4; j++) {
                int col = bn + wn + j * 16 + lm;
                float bv = bias[col];
                int rowb = bm + wm + i * 16 + lq * 4;   // 4 consecutive nodes
                int btq = rowb >> 10, node = rowb & 1023;
                *(unsigned long long*)&vT[((size_t)((btq * 8 + (col >> 6)) * 64 + (col & 63))) * 1024 + node] =
                    pk4(acc[i][j][0] + bv, acc[i][j][1] + bv,
                        acc[i][j][2] + bv, acc[i][j][3] + bv);
            }
        }
    }
}

// ------------- FFN GEMM (RELU or plain), swapped orientation -----------------
template <bool RELU>
__global__ __launch_bounds__(256) void gemm_bt(
    const bf16* __restrict__ A, const bf16* __restrict__ Bt,
    const float* __restrict__ bias, bf16* __restrict__ C)
{
    const int bm = blockIdx.x * 128, bn = blockIdx.y * 128;
    GEMM_BODY(SWAPPED)
#pragma unroll
    for (int i = 0; i < 4; i++) {
#pragma unroll
        for (int j = 0; j < 4; j++) {
            int row = bm + wm + i * 16 + lm;
            int colb = bn + wn + j * 16 + lq * 4;
            f32x4 b4 = *(const f32x4*)&bias[colb];
            float c0 = acc[i][j][0] + b4[0], c1 = acc[i][j][1] + b4[1];
            float c2 = acc[i][j][2] + b4[2], c3 = acc[i][j][3] + b4[3];
            if (RELU) {
                c0 = fmaxf(c0, 0.f); c1 = fmaxf(c1, 0.f);
                c2 = fmaxf(c2, 0.f); c3 = fmaxf(c3, 0.f);
            }
            *(unsigned long long*)&C[(size_t)row * 512 + colb] = pk4(c0, c1, c2, c3);
        }
    }
}

// ------------- flash attention: round-6 shape + post-barrier prefetch --------
// q (pre-scaled by log2e/8), k: [16384 x 512] bf16 ; vT: [(g)*64+d][1024] bf16
// o: [16384 x 512] f32.  grid(128 groups, 4 qtiles of 256 rows), 256 threads.
__global__ __launch_bounds__(256) void attn_kernel(
    const bf16* __restrict__ q, const bf16* __restrict__ k,
    const bf16* __restrict__ vT, float* __restrict__ o)
{
    constexpr int KP = 72;   // 144 B stride: 16-B aligned, free 2-way
    constexpr int VP = 72;
    __shared__ __align__(16) bf16 Ks[64 * KP];        // [key][d]
    __shared__ __align__(16) bf16 Vs[64 * VP];        // [d][key]
    __shared__ __align__(16) bf16 Ps[4][64 * VP];     // per-wave [q(64)][key]

    const int tid = threadIdx.x, lane = tid & 63, wave = tid >> 6;
    const int group = blockIdx.x;          // bt*8 + h
    const int bt = group >> 3, hh = group & 7;
    const int lm = lane & 15, lq = lane >> 4;
    const int qrow0 = bt * 1024 + blockIdx.y * 256 + wave * 64;

    u32x4 qf[4][2];
#pragma unroll
    for (int tm = 0; tm < 4; tm++)
#pragma unroll
        for (int kk2 = 0; kk2 < 2; kk2++)
            qf[tm][kk2] = *(const u32x4*)&q[(size_t)(qrow0 + tm * 16 + lm) * 512 + hh * 64 + kk2 * 32 + lq * 8];

    const bf16* kbase = k + (size_t)(bt * 1024) * 512 + hh * 64;   // + row*512 + e
    const bf16* vbase = vT + (size_t)group * 64 * 1024;            // + d*1024 + key
    bf16* Pw = Ps[wave];

    // staging coords (per thread, 2 chunks of 64-el rows)
    const int r0 = tid >> 3, e0 = (tid & 7) * 8;
    const int r1 = (256 + tid) >> 3, e1 = e0;

    f32x4 accO[4][4];
#pragma unroll
    for (int tm = 0; tm < 4; tm++)
#pragma unroll
        for (int tn = 0; tn < 4; tn++) accO[tm][tn] = (f32x4){0.f, 0.f, 0.f, 0.f};
    float part[4] = {0.f, 0.f, 0.f, 0.f};

    // prefetch kt=0
    u32x4 kreg0 = *(const u32x4*)&kbase[(size_t)r0 * 512 + e0];
    u32x4 kreg1 = *(const u32x4*)&kbase[(size_t)r1 * 512 + e1];
    u32x4 vreg0 = *(const u32x4*)&vbase[(size_t)r0 * 1024 + e0];
    u32x4 vreg1 = *(const u32x4*)&vbase[(size_t)r1 * 1024 + e1];

    for (int kt = 0; kt < 16; kt++) {
        __syncthreads();   // prior S/PV reads of Ks/Vs done (also drains prefetch)
        *(u32x4*)&Ks[r0 * KP + e0] = kreg0;
        *(u32x4*)&Ks[r1 * KP + e1] = kreg1;
        *(u32x4*)&Vs[r0 * VP + e0] = vreg0;
        *(u32x4*)&Vs[r1 * VP + e1] = vreg1;
        __syncthreads();   // staged tile visible
        if (kt < 15) {     // POST-barrier: loads stay in flight across compute
            const bf16* kn = kbase + (size_t)((kt + 1) * 64) * 512;
            const bf16* vn = vbase + (kt + 1) * 64;
            kreg0 = *(const u32x4*)&kn[(size_t)r0 * 512 + e0];
            kreg1 = *(const u32x4*)&kn[(size_t)r1 * 512 + e1];
            vreg0 = *(const u32x4*)&vn[(size_t)r0 * 1024 + e0];
            vreg1 = *(const u32x4*)&vn[(size_t)r1 * 1024 + e1];
        }

        // S^T tiles: A=K (m=key), B=Q (n=q); C-frag rows = 4 consecutive keys
#pragma unroll
        for (int tk = 0; tk < 4; tk++) {
            u32x4 kf0 = *(const u32x4*)&Ks[(tk * 16 + lm) * KP + lq * 8];
            u32x4 kf1 = *(const u32x4*)&Ks[(tk * 16 + lm) * KP + 32 + lq * 8];
#pragma unroll
            for (int tm = 0; tm < 4; tm++) {
                f32x4 st = (f32x4){0.f, 0.f, 0.f, 0.f};
                st = mfma16(kf0, qf[tm][0], st);
                st = mfma16(kf1, qf[tm][1], st);
                float p0 = __builtin_amdgcn_exp2f(st[0]);
                float p1 = __builtin_amdgcn_exp2f(st[1]);
                float p2 = __builtin_amdgcn_exp2f(st[2]);
                float p3 = __builtin_amdgcn_exp2f(st[3]);
                part[tm] += (p0 + p1) + (p2 + p3);
                unsigned lo = trunc2(p0, p1), hi = trunc2(p2, p3);
                unsigned long long pk2 = ((unsigned long long)hi << 32) | lo;
                *(unsigned long long*)&Pw[(tm * 16 + lm) * VP + tk * 16 + lq * 4] = pk2;
            }
        }

        // O += P V   (A=P from LDS, B=V^T from LDS)
#pragma unroll
        for (int kc = 0; kc < 2; kc++) {
            u32x4 pf[4], vf[4];
#pragma unroll
            for (int tm = 0; tm < 4; tm++)
                pf[tm] = *(const u32x4*)&Pw[(tm * 16 + lm) * VP + kc * 32 + lq * 8];
#pragma unroll
            for (int tn = 0; tn < 4; tn++)
                vf[tn] = *(const u32x4*)&Vs[(tn * 16 + lm) * VP + kc * 32 + lq * 8];
#pragma unroll
            for (int tm = 0; tm < 4; tm++)
#pragma unroll
                for (int tn = 0; tn < 4; tn++)
                    accO[tm][tn] = mfma16(pf[tm], vf[tn], accO[tm][tn]);
        }
    }

    // final l reduction (across quads) and normalized store
#pragma unroll
    for (int tm = 0; tm < 4; tm++) {
        part[tm] += __shfl_xor(part[tm], 16);
        part[tm] += __shfl_xor(part[tm], 32);
    }
#pragma unroll
    for (int tm = 0; tm < 4; tm++)
#pragma unroll
        for (int r = 0; r < 4; r++) {
            float l = __shfl(part[tm], lq * 4 + r);   // lane lq*4+r holds l for q-row lq*4+r
            float linv = 1.0f / l;
#pragma unroll
            for (int tn = 0; tn < 4; tn++) {
                int row = qrow0 + tm * 16 + lq * 4 + r;
                int col = hh * 64 + tn * 16 + lm;
                o[(size_t)row * 512 + col] = accO[tm][tn][r] * linv;
            }
        }
}

// ------------- LayerNorm (one wave per 512-el row) ---------------------------
template <bool AF32, bool RES, bool OF32>
__global__ __launch_bounds__(256) void ln_kernel(
    const void* __restrict__ a, const float* __restrict__ res,
    const float* __restrict__ g, const float* __restrict__ bb, void* __restrict__ out)
{
    int row = blockIdx.x * 4 + (threadIdx.x >> 6);
    int lane = threadIdx.x & 63;
    size_t base = (size_t)row * 512 + lane * 8;
    int cbase = lane * 8;

    float x8[8];
    if (AF32) {
        const float* af = (const float*)a;
        f32x4 lo = *(const f32x4*)&af[base];
        f32x4 hi = *(const f32x4*)&af[base + 4];
#pragma unroll
        for (int i = 0; i < 4; i++) { x8[i] = lo[i]; x8[4 + i] = hi[i]; }
    } else {
        bf8 av = __builtin_bit_cast(bf8, *(const u32x4*)&((const bf16*)a)[base]);
#pragma unroll
        for (int i = 0; i < 8; i++) x8[i] = __bfloat162float(av.h[i]);
    }
    if (RES) {
        f32x4 lo = *(const f32x4*)&res[base];
        f32x4 hi = *(const f32x4*)&res[base + 4];
#pragma unroll
        for (int i = 0; i < 4; i++) { x8[i] += lo[i]; x8[4 + i] += hi[i]; }
    }

    float s = 0.f, s2 = 0.f;
#pragma unroll
    for (int i = 0; i < 8; i++) { s += x8[i]; s2 += x8[i] * x8[i]; }
#pragma unroll
    for (int off = 1; off < 64; off <<= 1) {
        s += __shfl_xor(s, off);
        s2 += __shfl_xor(s2, off);
    }
    float mean = s * (1.f / 512.f);
    float var = s2 * (1.f / 512.f) - mean * mean;
    float rstd = rsqrtf(var + 1e-5f);

    f32x4 g0 = *(const f32x4*)&g[cbase], g1 = *(const f32x4*)&g[cbase + 4];
    f32x4 b0 = *(const f32x4*)&bb[cbase], b1v = *(const f32x4*)&bb[cbase + 4];
    float y[8];
#pragma unroll
    for (int i = 0; i < 4; i++) {
        y[i] = (x8[i] - mean) * rstd * g0[i] + b0[i];
        y[4 + i] = (x8[4 + i] - mean) * rstd * g1[i] + b1v[i];
    }
    if (OF32) {
        float* op = (float*)out;
        *(f32x4*)&op[base] = (f32x4){y[0], y[1], y[2], y[3]};
        *(f32x4*)&op[base + 4] = (f32x4){y[4], y[5], y[6], y[7]};
    } else {
        bf8 ov;
#pragma unroll
        for (int i = 0; i < 8; i++) ov.h[i] = __float2bfloat16(y[i]);
        *(u32x4*)&((bf16*)out)[base] = __builtin_bit_cast(u32x4, ov);
    }
}

// ------------- launch --------------------------------------------------------
extern "C" void kernel_launch(void* const* d_in, const int* in_sizes, int n_in,
                              void* d_out, int out_size, void* d_ws, size_t ws_size,
                              hipStream_t stream)
{
    const float* x    = (const float*)d_in[0];
    const float* Wq   = (const float*)d_in[1];
    const float* bq   = (const float*)d_in[2];
    const float* Wk   = (const float*)d_in[3];
    const float* bk   = (const float*)d_in[4];
    const float* Wv   = (const float*)d_in[5];
    const float* bv   = (const float*)d_in[6];
    const float* ln_g = (const float*)d_in[7];
    const float* ln_b = (const float*)d_in[8];
    const float* W1   = (const float*)d_in[9];
    const float* b1   = (const float*)d_in[10];
    const float* W2   = (const float*)d_in[11];
    const float* b2   = (const float*)d_in[12];
    const float* lnffg = (const float*)d_in[13];
    const float* lnffb = (const float*)d_in[14];
    float* out = (float*)d_out;

    bf16* ws = (bf16*)d_ws;
    bf16* WT = ws;                        // 5 * 262144 bf16
    bf16* qb = ws + 5 * 262144;           // 8388608 bf16 each below
    bf16* kb = qb + 8388608;
    bf16* vT = kb + 8388608;
    bf16* vl = qb;                        // reuse (q dead after attention)
    bf16* f1 = kb;                        // reuse (k dead after attention)
    bf16* f2 = vT;                        // reuse (v dead after attention)
    bf16* xb = (bf16*)d_out;              // 16.7MB scratch; dead before attention writes O

    prep<<<9216, 256, 0, stream>>>(Wq, Wk, Wv, W1, W2, x, WT, xb);

    gemm_qkv<<<dim3(128, 12), 256, 0, stream>>>(xb, WT, bq, bk, bv, qb, kb, vT);

    attn_kernel<<<dim3(128, 4), 256, 0, stream>>>(qb, kb, vT, out);

    ln_kernel<true, true, false><<<4096, 256, 0, stream>>>(out, x, ln_g, ln_b, vl);

    dim3 gg(128, 4);
    gemm_bt<true> <<<gg, 256, 0, stream>>>(vl, WT + 3 * 262144, b1, f1);
    gemm_bt<false><<<gg, 256, 0, stream>>>(f1, WT + 4 * 262144, b2, f2);

    ln_kernel<false, false, true><<<4096, 256, 0, stream>>>(f2, nullptr, lnffg, lnffb, out);
}